// Round 4
// baseline (744.590 us; speedup 1.0000x reference)
//
#include <hip/hip_runtime.h>

typedef __attribute__((ext_vector_type(8))) short bf16x8;
typedef __attribute__((ext_vector_type(4))) short bf16x4;
typedef __attribute__((ext_vector_type(4))) float f32x4;

#if __has_builtin(__builtin_amdgcn_exp2f)
#define EXP2(x) __builtin_amdgcn_exp2f(x)
#else
#define EXP2(x) exp2f(x)
#endif

// PV matmul: 16x16x16 bf16 (B-operand layout == QK C/D layout -> no transpose)
#if __has_builtin(__builtin_amdgcn_mfma_f32_16x16x16bf16_1k)
#define PV_MFMA(a, b, c) __builtin_amdgcn_mfma_f32_16x16x16bf16_1k(a, b, c, 0, 0, 0)
#else
static __device__ __forceinline__ f32x4 pv_mfma_asm(bf16x4 a, bf16x4 b, f32x4 c) {
    asm("v_mfma_f32_16x16x16_bf16 %0, %1, %2, %0" : "+v"(c) : "v"(a), "v"(b));
    return c;
}
#define PV_MFMA(a, b, c) pv_mfma_asm(a, b, c)
#endif

__device__ __forceinline__ unsigned short f2bf(float f) {
    union { float f; unsigned int u; } v; v.f = f;
    unsigned int r = v.u + 0x7fffu + ((v.u >> 16) & 1u);
    return (unsigned short)(r >> 16);
}

__device__ __forceinline__ float asf(unsigned int u) {
    union { unsigned int u; float f; } v; v.u = u; return v.f;
}

// sqrt( (1/sqrt(32)) * log2(e) ) — baked into BOTH xqT operands so QK^T
// emerges pre-multiplied by scale*log2e: exp2(score) == softmax numerator.
#define QK_PRESCALE 0.50500983f

// ---------------------------------------------------------------------------
// Kernel 1: grouped 1x1 conv.  x[h][i][n] = sum_j W[g][i][j] p[h][j][n] + b
// Writes xqT [h][n][i] (bf16, i contiguous, PRE-SCALED)  -> QK MFMA operands
//        xv  [h][i][n] (bf16, n contiguous)              -> PV A-op (V=elu(x))
// ---------------------------------------------------------------------------
__global__ __launch_bounds__(256) void conv_kernel(
    const float* __restrict__ points, const float* __restrict__ conv_w,
    const float* __restrict__ conv_b,
    unsigned short* __restrict__ xqT, unsigned short* __restrict__ xv)
{
    __shared__ float w[1024];
    const int h  = blockIdx.x >> 4;   // 16 heads
    const int nc = blockIdx.x & 15;   // 16 n-chunks of 256
    const int g  = h & 7;
    const int tid = threadIdx.x;
    const float* wg = conv_w + g * 1024;
    for (int k = tid; k < 1024; k += 256) w[k] = wg[k];
    __syncthreads();
    const int n = nc * 256 + tid;
    const float* p = points + (size_t)h * 32 * 4096 + n;
    float pv[32];
#pragma unroll
    for (int j = 0; j < 32; ++j) pv[j] = p[(size_t)j * 4096];
    float out[32];
#pragma unroll
    for (int i = 0; i < 32; ++i) {
        float acc = conv_b[g * 32 + i];
#pragma unroll
        for (int j = 0; j < 32; ++j) acc += w[i * 32 + j] * pv[j];
        out[i] = acc;
    }
    unsigned short tq[32];
#pragma unroll
    for (int i = 0; i < 32; ++i) tq[i] = f2bf(out[i] * QK_PRESCALE);
    bf16x8* dst = (bf16x8*)(xqT + ((size_t)h * 4096 + n) * 32);
#pragma unroll
    for (int t = 0; t < 4; ++t) dst[t] = ((bf16x8*)tq)[t];
#pragma unroll
    for (int i = 0; i < 32; ++i) {
        float x = out[i];
        float e = x > 0.f ? x : (__expf(x) - 1.f);   // elu
        xv[((size_t)h * 32 + i) * 4096 + n] = f2bf(e);
    }
}

// ---------------------------------------------------------------------------
// Kernel 2: flash attention. R1 grid/staging structure (1024 blocks, 4 bl/CU)
// + VALU diet + DIRECT P feed:
//   QK: mfma_f32_16x16x32_bf16 -> S C/D regs (col=m=l15, row n=quad*4+r)
//   PV: mfma_f32_16x16x16_bf16 -> B-operand layout (col=l15, k=quad*4+j)
//       == QK C/D layout, so exp'd scores go straight in. No P LDS at all.
// No-max softmax (|log2 scores| << 126). Fused GroupNorm partial stats.
// ---------------------------------------------------------------------------
#define KSTR 40    // 32 + 8 pad shorts
#define VSTR 72    // 64 + 8 pad shorts

__device__ __forceinline__ bf16x4 exp_pack(f32x4 sc, float& lsum) {
    union { float f; unsigned int u; } e0, e1, e2, e3;
    e0.f = EXP2(sc[0]); e1.f = EXP2(sc[1]); e2.f = EXP2(sc[2]); e3.f = EXP2(sc[3]);
    unsigned int t0 = e0.u & 0xffff0000u, t1 = e1.u & 0xffff0000u;
    unsigned int t2 = e2.u & 0xffff0000u, t3 = e3.u & 0xffff0000u;
    // denominator over the TRUNCATED values -> weights sum to exactly 1
    lsum += (asf(t0) + asf(t1)) + (asf(t2) + asf(t3));
    union { unsigned int d[2]; bf16x4 v; } pk;
    pk.d[0] = (t0 >> 16) | t1;
    pk.d[1] = (t2 >> 16) | t3;
    return pk.v;
}

__global__ __launch_bounds__(256) void attn_kernel(
    const unsigned short* __restrict__ xqT,
    const unsigned short* __restrict__ xv,
    const float* __restrict__ points,
    float* __restrict__ z, float* __restrict__ stats)
{
    __shared__ unsigned short Kt[64 * KSTR];   // [n][i]  5120 B
    __shared__ unsigned short Vt[32 * VSTR];   // [i][n]  4608 B

    const int h  = blockIdx.y;
    const int b = h >> 3, g = h & 7;
    const int tid = threadIdx.x;
    const int wv = tid >> 6, lane = tid & 63;
    const int quad = lane >> 4, l15 = lane & 15;

    const int m = blockIdx.x * 64 + wv * 16 + l15;   // this lane's query col

    const unsigned short* kbase = xqT + (size_t)h * 4096 * 32;
    const unsigned short* vbase = xv  + (size_t)h * 32 * 4096;

    // Q fragment (B-operand of 16x16x32): col=l15, k=quad*8+j
    const bf16x8 qfrag = *(const bf16x8*)(kbase + (size_t)m * 32 + quad * 8);

    f32x4 acc0 = {0, 0, 0, 0};   // O rows i = 0..15
    f32x4 acc1 = {0, 0, 0, 0};   // O rows i = 16..31
    float lsum = 0.f;

    const int kr = tid >> 2, kc = (tid & 3) * 8;   // K staging [n][i]
    const int vi = tid >> 3, vn = (tid & 7) * 8;   // V staging [i][n]

    // hoisted LDS read bases (byte-exact const offsets added in-loop)
    const unsigned short* krow  = Kt + (size_t)l15 * KSTR + quad * 8;
    const unsigned short* vrow0 = Vt + (size_t)l15 * VSTR + quad * 4;
    const unsigned short* vrow1 = Vt + (size_t)(16 + l15) * VSTR + quad * 4;

    for (int n0 = 0; n0 < 4096; n0 += 64) {
        __syncthreads();
        *(bf16x8*)(Kt + kr * KSTR + kc) =
            *(const bf16x8*)(kbase + (size_t)(n0 + kr) * 32 + kc);
        *(bf16x8*)(Vt + vi * VSTR + vn) =
            *(const bf16x8*)(vbase + (size_t)vi * 4096 + n0 + vn);
        __syncthreads();

#pragma unroll
        for (int s = 0; s < 4; ++s) {
            // QK A-operand K^T: A[r=n][k=i], lane r=l15 -> n = s*16+l15
            const bf16x8 kf = *(const bf16x8*)(krow + s * 16 * KSTR);
            f32x4 sc = __builtin_amdgcn_mfma_f32_16x16x32_bf16(
                kf, qfrag, (f32x4){0, 0, 0, 0}, 0, 0, 0);
            // S C/D: col=m=l15, row-in-step = quad*4+r  == PV B-operand slot
            bf16x4 pf = exp_pack(sc, lsum);
            // PV A-operand V: A[r=i][k=n-in-step=quad*4+j]
            bf16x4 v0 = *(const bf16x4*)(vrow0 + s * 16);
            bf16x4 v1 = *(const bf16x4*)(vrow1 + s * 16);
            acc0 = PV_MFMA(v0, pf, acc0);
            acc1 = PV_MFMA(v1, pf, acc1);
        }
    }

    // denominator: sum partials over the 4 quads sharing column m
    lsum += __shfl_xor(lsum, 16, 64);
    lsum += __shfl_xor(lsum, 32, 64);
    const float inv = 1.f / lsum;

    const float* pb = points + (size_t)b * 256 * 4096;
    float* zb = z + (size_t)b * 256 * 4096;
    float* sb = stats + (size_t)b * 64;

#pragma unroll
    for (int half = 0; half < 2; ++half) {
        f32x4 a = half ? acc1 : acc0;
#pragma unroll
        for (int r = 0; r < 4; ++r) {
            const int i = half * 16 + quad * 4 + r;        // C/D row; == gn group
            const size_t off = (size_t)(i * 8 + g) * 4096; // channel shuffle
            float zA = a[r] * inv + pb[off + m];
            zb[off + m] = zA;
            // fused GroupNorm partial stats over the 16 l15 lanes
            float s  = zA;
            float ss = zA * zA;
            s += __shfl_xor(s, 1, 64);  ss += __shfl_xor(ss, 1, 64);
            s += __shfl_xor(s, 2, 64);  ss += __shfl_xor(ss, 2, 64);
            s += __shfl_xor(s, 4, 64);  ss += __shfl_xor(ss, 4, 64);
            s += __shfl_xor(s, 8, 64);  ss += __shfl_xor(ss, 8, 64);
            if (l15 == 0) {
                atomicAdd(&sb[i * 2], s);
                atomicAdd(&sb[i * 2 + 1], ss);
            }
        }
    }
}

// ---------------------------------------------------------------------------
// Kernel 3: GroupNorm apply, in place on d_out, from fused atomic sums.
// ---------------------------------------------------------------------------
__global__ __launch_bounds__(256) void gn_apply(float* __restrict__ z,
                                                const float* __restrict__ stats,
                                                const float* __restrict__ gw,
                                                const float* __restrict__ gb)
{
    const int idx = blockIdx.x * 256 + threadIdx.x;  // float4 index
    float4* p = (float4*)z;
    float4 v = p[idx];
    const int chg = idx >> 10;       // global channel b*256+ch
    const int blk = chg >> 3;        // stats slot = b*32 + ch/8
    const int ch  = chg & 255;
    const float s = stats[blk * 2], ss = stats[blk * 2 + 1];
    const float mean = s * (1.f / 32768.f);
    const float var  = ss * (1.f / 32768.f) - mean * mean;
    const float rstd = rsqrtf(var + 1e-5f);
    const float w  = gw[ch] * rstd;
    const float bb = gb[ch] - mean * w;
    v.x = v.x * w + bb; v.y = v.y * w + bb;
    v.z = v.z * w + bb; v.w = v.w * w + bb;
    p[idx] = v;
}

extern "C" void kernel_launch(void* const* d_in, const int* in_sizes, int n_in,
                              void* d_out, int out_size, void* d_ws, size_t ws_size,
                              hipStream_t stream)
{
    const float* points = (const float*)d_in[0];
    const float* conv_w = (const float*)d_in[1];
    const float* conv_b = (const float*)d_in[2];
    const float* gn_w   = (const float*)d_in[3];
    const float* gn_b   = (const float*)d_in[4];
    float* out = (float*)d_out;
    char* ws = (char*)d_ws;
    unsigned short* xqT = (unsigned short*)ws;                             // 4 MB
    unsigned short* xv  = (unsigned short*)(ws + (size_t)4 * 1024 * 1024); // 4 MB
    float* stats = (float*)(ws + (size_t)8 * 1024 * 1024);                 // 512 B

    hipMemsetAsync(stats, 0, 64 * 2 * sizeof(float), stream);
    conv_kernel<<<256, 256, 0, stream>>>(points, conv_w, conv_b, xqT, xv);
    attn_kernel<<<dim3(64, 16), 256, 0, stream>>>(xqT, xv, points, out, stats);
    gn_apply<<<2048, 256, 0, stream>>>(out, stats, gn_w, gn_b);
}

// Round 5
// 707.633 us; speedup vs baseline: 1.0522x; 1.0522x over previous
//
#include <hip/hip_runtime.h>

typedef __attribute__((ext_vector_type(8))) short bf16x8;
typedef __attribute__((ext_vector_type(4))) short bf16x4;
typedef __attribute__((ext_vector_type(4))) float f32x4;

#if __has_builtin(__builtin_amdgcn_exp2f)
#define EXP2(x) __builtin_amdgcn_exp2f(x)
#else
#define EXP2(x) exp2f(x)
#endif

__device__ __forceinline__ unsigned short f2bf(float f) {
    union { float f; unsigned int u; } v; v.f = f;
    unsigned int r = v.u + 0x7fffu + ((v.u >> 16) & 1u);
    return (unsigned short)(r >> 16);
}

__device__ __forceinline__ float asf(unsigned int u) {
    union { unsigned int u; float f; } v; v.u = u; return v.f;
}

// sqrt( (1/sqrt(32)) * log2(e) ) — baked into BOTH xqT operands so QK^T
// emerges pre-multiplied by scale*log2e: exp2(raw score) == softmax numerator.
#define QK_PRESCALE 0.50500983f

// ---------------------------------------------------------------------------
// Kernel 1: grouped 1x1 conv.  x[h][i][n] = sum_j W[g][i][j] p[h][j][n] + b
// Writes xqT [h][n][i] (bf16, i contiguous, PRE-SCALED)  -> QK MFMA operands
//        xv  [h][i][n] (bf16, n contiguous)              -> PV A-op (V=elu(x))
// ---------------------------------------------------------------------------
__global__ __launch_bounds__(256) void conv_kernel(
    const float* __restrict__ points, const float* __restrict__ conv_w,
    const float* __restrict__ conv_b,
    unsigned short* __restrict__ xqT, unsigned short* __restrict__ xv)
{
    __shared__ float w[1024];
    const int h  = blockIdx.x >> 4;   // 16 heads
    const int nc = blockIdx.x & 15;   // 16 n-chunks of 256
    const int g  = h & 7;
    const int tid = threadIdx.x;
    const float* wg = conv_w + g * 1024;
    for (int k = tid; k < 1024; k += 256) w[k] = wg[k];
    __syncthreads();
    const int n = nc * 256 + tid;
    const float* p = points + (size_t)h * 32 * 4096 + n;
    float pv[32];
#pragma unroll
    for (int j = 0; j < 32; ++j) pv[j] = p[(size_t)j * 4096];
    float out[32];
#pragma unroll
    for (int i = 0; i < 32; ++i) {
        float acc = conv_b[g * 32 + i];
#pragma unroll
        for (int j = 0; j < 32; ++j) acc += w[i * 32 + j] * pv[j];
        out[i] = acc;
    }
    unsigned short tq[32];
#pragma unroll
    for (int i = 0; i < 32; ++i) tq[i] = f2bf(out[i] * QK_PRESCALE);
    bf16x8* dst = (bf16x8*)(xqT + ((size_t)h * 4096 + n) * 32);
#pragma unroll
    for (int t = 0; t < 4; ++t) dst[t] = ((bf16x8*)tq)[t];
#pragma unroll
    for (int i = 0; i < 32; ++i) {
        float x = out[i];
        float e = x > 0.f ? x : (__expf(x) - 1.f);   // elu
        xv[((size_t)h * 32 + i) * 4096 + n] = f2bf(e);
    }
}

// ---------------------------------------------------------------------------
// Kernel 2: flash attention — EXACT R1 structure (measured best: 114.9us,
// VALUBusy 61%) with only the per-score VALU diet + fused GN stats epilogue.
//   S = K^T Q via 16x16x32 MFMA (K=32=headdim), P exp'd + packed to bf16,
//   per-wave LDS round-trip (C/D layout -> B-operand layout), PV via two
//   16x16x32 MFMAs per 32-key group. No-max softmax (|log2 scores| << 126).
// ---------------------------------------------------------------------------
#define KSTR 40   // 32 + 8 pad shorts
#define VSTR 72   // 64 + 8 pad shorts
#define PSTR 72   // 64 + 8 pad shorts

__device__ __forceinline__ bf16x4 exp_pack(f32x4 sc, float& lsum) {
    union { float f; unsigned int u; } e0, e1, e2, e3;
    e0.f = EXP2(sc[0]); e1.f = EXP2(sc[1]); e2.f = EXP2(sc[2]); e3.f = EXP2(sc[3]);
    unsigned int t0 = e0.u & 0xffff0000u, t1 = e1.u & 0xffff0000u;
    unsigned int t2 = e2.u & 0xffff0000u, t3 = e3.u & 0xffff0000u;
    // denominator over the TRUNCATED values -> weights sum to exactly 1
    lsum += (asf(t0) + asf(t1)) + (asf(t2) + asf(t3));
    union { unsigned int d[2]; bf16x4 v; } pk;
    pk.d[0] = (t0 >> 16) | t1;
    pk.d[1] = (t2 >> 16) | t3;
    return pk.v;
}

__global__ __launch_bounds__(256) void attn_kernel(
    const unsigned short* __restrict__ xqT,
    const unsigned short* __restrict__ xv,
    const float* __restrict__ points,
    float* __restrict__ z, float* __restrict__ stats)
{
    __shared__ unsigned short Kt[64 * KSTR];    // [n][i]
    __shared__ unsigned short Vt[32 * VSTR];    // [i][n]
    __shared__ unsigned short Pl[4][16 * PSTR]; // per-wave [m][n]

    const int h  = blockIdx.y;
    const int b = h >> 3, g = h & 7;
    const int tid = threadIdx.x;
    const int wv = tid >> 6, lane = tid & 63;
    const int quad = lane >> 4, l15 = lane & 15;

    const int m = blockIdx.x * 64 + wv * 16 + l15;   // this lane's query col

    const unsigned short* kbase = xqT + (size_t)h * 4096 * 32;
    const unsigned short* vbase = xv  + (size_t)h * 32 * 4096;

    // Q fragment (B-operand): col=l15, k=quad*8+j
    const bf16x8 qfrag = *(const bf16x8*)(kbase + (size_t)m * 32 + quad * 8);

    f32x4 acc0 = {0.f, 0.f, 0.f, 0.f};   // O rows i = 0..15
    f32x4 acc1 = {0.f, 0.f, 0.f, 0.f};   // O rows i = 16..31
    float lsum = 0.f;

    const int kr = tid >> 2, kc = (tid & 3) * 8;   // K staging: [n][i]
    const int vi = tid >> 3, vn = (tid & 7) * 8;   // V staging: [i][n]

    unsigned short* pw = &Pl[wv][0];

    for (int n0 = 0; n0 < 4096; n0 += 64) {
        __syncthreads();
        *(bf16x8*)(Kt + kr * KSTR + kc) =
            *(const bf16x8*)(kbase + (size_t)(n0 + kr) * 32 + kc);
        *(bf16x8*)(Vt + vi * VSTR + vn) =
            *(const bf16x8*)(vbase + (size_t)vi * 4096 + n0 + vn);
        __syncthreads();

#pragma unroll
        for (int s = 0; s < 4; ++s) {
            // A-operand K^T: A[r=n][k=i], lane r=l15 -> n = s*16+l15
            bf16x8 kf = *(const bf16x8*)(Kt + (s * 16 + l15) * KSTR + quad * 8);
            f32x4 sc = __builtin_amdgcn_mfma_f32_16x16x32_bf16(
                kf, qfrag, (f32x4){0.f, 0.f, 0.f, 0.f}, 0, 0, 0);
            // C/D: col=m=l15, row n = s*16 + quad*4 + r
            bf16x4 pk = exp_pack(sc, lsum);
            *(bf16x4*)(pw + l15 * PSTR + s * 16 + quad * 4) = pk;
        }
        // intra-wave LDS write->read: ordered via lgkmcnt (compiler-inserted)
#pragma unroll
        for (int ng = 0; ng < 2; ++ng) {
            // B-operand P: B[k=n][col=m], lane: col=l15, k = ng*32+quad*8+j
            bf16x8 pf = *(const bf16x8*)(pw + l15 * PSTR + ng * 32 + quad * 8);
            // A-operand V: A[r=i][k=n]
            bf16x8 v0 = *(const bf16x8*)(Vt + l15 * VSTR + ng * 32 + quad * 8);
            bf16x8 v1 = *(const bf16x8*)(Vt + (16 + l15) * VSTR + ng * 32 + quad * 8);
            acc0 = __builtin_amdgcn_mfma_f32_16x16x32_bf16(v0, pf, acc0, 0, 0, 0);
            acc1 = __builtin_amdgcn_mfma_f32_16x16x32_bf16(v1, pf, acc1, 0, 0, 0);
        }
    }

    // denominator: sum partial l over the 4 quads sharing column m
    lsum += __shfl_xor(lsum, 16, 64);
    lsum += __shfl_xor(lsum, 32, 64);
    const float inv = 1.f / lsum;

    const float* pb = points + (size_t)b * 256 * 4096;
    float* zb = z + (size_t)b * 256 * 4096;
    float* sb = stats + (size_t)b * 64;

#pragma unroll
    for (int half = 0; half < 2; ++half) {
        f32x4 a = half ? acc1 : acc0;
#pragma unroll
        for (int r = 0; r < 4; ++r) {
            const int i = half * 16 + quad * 4 + r;        // C/D row; == gn group
            const size_t off = (size_t)(i * 8 + g) * 4096; // channel shuffle
            float zA = a[r] * inv + pb[off + m];
            zb[off + m] = zA;
            // fused GroupNorm partial stats over the 16 l15 lanes
            float s  = zA;
            float ss = zA * zA;
            s += __shfl_xor(s, 1, 64);  ss += __shfl_xor(ss, 1, 64);
            s += __shfl_xor(s, 2, 64);  ss += __shfl_xor(ss, 2, 64);
            s += __shfl_xor(s, 4, 64);  ss += __shfl_xor(ss, 4, 64);
            s += __shfl_xor(s, 8, 64);  ss += __shfl_xor(ss, 8, 64);
            if (l15 == 0) {
                atomicAdd(&sb[i * 2], s);
                atomicAdd(&sb[i * 2 + 1], ss);
            }
        }
    }
}

// ---------------------------------------------------------------------------
// Kernel 3: GroupNorm apply, in place on d_out, from fused atomic sums.
// ---------------------------------------------------------------------------
__global__ __launch_bounds__(256) void gn_apply(float* __restrict__ z,
                                                const float* __restrict__ stats,
                                                const float* __restrict__ gw,
                                                const float* __restrict__ gb)
{
    const int idx = blockIdx.x * 256 + threadIdx.x;  // float4 index
    float4* p = (float4*)z;
    float4 v = p[idx];
    const int chg = idx >> 10;       // global channel b*256+ch
    const int blk = chg >> 3;        // stats slot = b*32 + ch/8
    const int ch  = chg & 255;
    const float s = stats[blk * 2], ss = stats[blk * 2 + 1];
    const float mean = s * (1.f / 32768.f);
    const float var  = ss * (1.f / 32768.f) - mean * mean;
    const float rstd = rsqrtf(var + 1e-5f);
    const float w  = gw[ch] * rstd;
    const float bb = gb[ch] - mean * w;
    v.x = v.x * w + bb; v.y = v.y * w + bb;
    v.z = v.z * w + bb; v.w = v.w * w + bb;
    p[idx] = v;
}

extern "C" void kernel_launch(void* const* d_in, const int* in_sizes, int n_in,
                              void* d_out, int out_size, void* d_ws, size_t ws_size,
                              hipStream_t stream)
{
    const float* points = (const float*)d_in[0];
    const float* conv_w = (const float*)d_in[1];
    const float* conv_b = (const float*)d_in[2];
    const float* gn_w   = (const float*)d_in[3];
    const float* gn_b   = (const float*)d_in[4];
    float* out = (float*)d_out;
    char* ws = (char*)d_ws;
    unsigned short* xqT = (unsigned short*)ws;                             // 4 MB
    unsigned short* xv  = (unsigned short*)(ws + (size_t)4 * 1024 * 1024); // 4 MB
    float* stats = (float*)(ws + (size_t)8 * 1024 * 1024);                 // 512 B

    hipMemsetAsync(stats, 0, 64 * 2 * sizeof(float), stream);
    conv_kernel<<<256, 256, 0, stream>>>(points, conv_w, conv_b, xqT, xv);
    attn_kernel<<<dim3(64, 16), 256, 0, stream>>>(xqT, xv, points, out, stats);
    gn_apply<<<2048, 256, 0, stream>>>(out, stats, gn_w, gn_b);
}

// Round 6
// 190.698 us; speedup vs baseline: 3.9045x; 3.7107x over previous
//
#include <hip/hip_runtime.h>

typedef __attribute__((ext_vector_type(8))) short bf16x8;
typedef __attribute__((ext_vector_type(4))) short bf16x4;
typedef __attribute__((ext_vector_type(4))) float f32x4;

#if __has_builtin(__builtin_amdgcn_exp2f)
#define EXP2(x) __builtin_amdgcn_exp2f(x)
#else
#define EXP2(x) exp2f(x)
#endif

__device__ __forceinline__ unsigned short f2bf(float f) {
    union { float f; unsigned int u; } v; v.f = f;
    unsigned int r = v.u + 0x7fffu + ((v.u >> 16) & 1u);
    return (unsigned short)(r >> 16);
}

__device__ __forceinline__ float asf(unsigned int u) {
    union { unsigned int u; float f; } v; v.u = u; return v.f;
}

// sqrt( (1/sqrt(32)) * log2(e) ) — baked into BOTH xqT operands so QK^T
// emerges pre-multiplied by scale*log2e: exp2(raw score) == softmax numerator.
#define QK_PRESCALE 0.50500983f

// ---------------------------------------------------------------------------
// Kernel 1: grouped 1x1 conv.  x[h][i][n] = sum_j W[g][i][j] p[h][j][n] + b
// Writes xqT [h][n][i] (bf16, i contiguous, PRE-SCALED)  -> QK MFMA operands
//        xv  [h][i][n] (bf16, n contiguous)              -> PV A-op (V=elu(x))
// ---------------------------------------------------------------------------
__global__ __launch_bounds__(256) void conv_kernel(
    const float* __restrict__ points, const float* __restrict__ conv_w,
    const float* __restrict__ conv_b,
    unsigned short* __restrict__ xqT, unsigned short* __restrict__ xv)
{
    __shared__ float w[1024];
    const int h  = blockIdx.x >> 4;   // 16 heads
    const int nc = blockIdx.x & 15;   // 16 n-chunks of 256
    const int g  = h & 7;
    const int tid = threadIdx.x;
    const float* wg = conv_w + g * 1024;
    for (int k = tid; k < 1024; k += 256) w[k] = wg[k];
    __syncthreads();
    const int n = nc * 256 + tid;
    const float* p = points + (size_t)h * 32 * 4096 + n;
    float pv[32];
#pragma unroll
    for (int j = 0; j < 32; ++j) pv[j] = p[(size_t)j * 4096];
    float out[32];
#pragma unroll
    for (int i = 0; i < 32; ++i) {
        float acc = conv_b[g * 32 + i];
#pragma unroll
        for (int j = 0; j < 32; ++j) acc += w[i * 32 + j] * pv[j];
        out[i] = acc;
    }
    unsigned short tq[32];
#pragma unroll
    for (int i = 0; i < 32; ++i) tq[i] = f2bf(out[i] * QK_PRESCALE);
    bf16x8* dst = (bf16x8*)(xqT + ((size_t)h * 4096 + n) * 32);
#pragma unroll
    for (int t = 0; t < 4; ++t) dst[t] = ((bf16x8*)tq)[t];
#pragma unroll
    for (int i = 0; i < 32; ++i) {
        float x = out[i];
        float e = x > 0.f ? x : (__expf(x) - 1.f);   // elu
        xv[((size_t)h * 32 + i) * 4096 + n] = f2bf(e);
    }
}

// ---------------------------------------------------------------------------
// Kernel 2: flash attention — EXACT R1 structure (measured: 114.9us,
// VALUBusy 61%, MfmaUtil 12.5%, occ 39%). Only change vs R1: per-score
// VALU diet (pre-scaled operands -> raw MFMA output is log2-domain, one
// v_exp_f32 per score; truncation-pack instead of RNE; denominator over
// truncated values so weights sum to exactly 1).
// NO atomic epilogue — R3/R4/R5 showed 262k same-line device atomics add
// ~500us of serialized tail. GroupNorm stats run as a separate tiny pass.
// ---------------------------------------------------------------------------
#define KSTR 40   // 32 + 8 pad shorts
#define VSTR 72   // 64 + 8 pad shorts
#define PSTR 72   // 64 + 8 pad shorts

__device__ __forceinline__ bf16x4 exp_pack(f32x4 sc, float& lsum) {
    union { float f; unsigned int u; } e0, e1, e2, e3;
    e0.f = EXP2(sc[0]); e1.f = EXP2(sc[1]); e2.f = EXP2(sc[2]); e3.f = EXP2(sc[3]);
    unsigned int t0 = e0.u & 0xffff0000u, t1 = e1.u & 0xffff0000u;
    unsigned int t2 = e2.u & 0xffff0000u, t3 = e3.u & 0xffff0000u;
    lsum += (asf(t0) + asf(t1)) + (asf(t2) + asf(t3));
    union { unsigned int d[2]; bf16x4 v; } pk;
    pk.d[0] = (t0 >> 16) | t1;
    pk.d[1] = (t2 >> 16) | t3;
    return pk.v;
}

__global__ __launch_bounds__(256) void attn_kernel(
    const unsigned short* __restrict__ xqT,
    const unsigned short* __restrict__ xv,
    const float* __restrict__ points,
    float* __restrict__ z)
{
    __shared__ unsigned short Kt[64 * KSTR];    // [n][i]
    __shared__ unsigned short Vt[32 * VSTR];    // [i][n]
    __shared__ unsigned short Pl[4][16 * PSTR]; // per-wave [m][n]

    const int h  = blockIdx.y;
    const int b = h >> 3, g = h & 7;
    const int tid = threadIdx.x;
    const int wv = tid >> 6, lane = tid & 63;
    const int quad = lane >> 4, l15 = lane & 15;

    const int m = blockIdx.x * 64 + wv * 16 + l15;   // this lane's query col

    const unsigned short* kbase = xqT + (size_t)h * 4096 * 32;
    const unsigned short* vbase = xv  + (size_t)h * 32 * 4096;

    // Q fragment (B-operand): col=l15, k=quad*8+j
    const bf16x8 qfrag = *(const bf16x8*)(kbase + (size_t)m * 32 + quad * 8);

    f32x4 acc0 = {0.f, 0.f, 0.f, 0.f};   // O rows i = 0..15
    f32x4 acc1 = {0.f, 0.f, 0.f, 0.f};   // O rows i = 16..31
    float lsum = 0.f;

    const int kr = tid >> 2, kc = (tid & 3) * 8;   // K staging: [n][i]
    const int vi = tid >> 3, vn = (tid & 7) * 8;   // V staging: [i][n]

    unsigned short* pw = &Pl[wv][0];

    for (int n0 = 0; n0 < 4096; n0 += 64) {
        __syncthreads();
        *(bf16x8*)(Kt + kr * KSTR + kc) =
            *(const bf16x8*)(kbase + (size_t)(n0 + kr) * 32 + kc);
        *(bf16x8*)(Vt + vi * VSTR + vn) =
            *(const bf16x8*)(vbase + (size_t)vi * 4096 + n0 + vn);
        __syncthreads();

#pragma unroll
        for (int s = 0; s < 4; ++s) {
            // A-operand K^T: A[r=n][k=i], lane r=l15 -> n = s*16+l15
            bf16x8 kf = *(const bf16x8*)(Kt + (s * 16 + l15) * KSTR + quad * 8);
            f32x4 sc = __builtin_amdgcn_mfma_f32_16x16x32_bf16(
                kf, qfrag, (f32x4){0.f, 0.f, 0.f, 0.f}, 0, 0, 0);
            // C/D: col=m=l15, row n = s*16 + quad*4 + r
            bf16x4 pk = exp_pack(sc, lsum);
            *(bf16x4*)(pw + l15 * PSTR + s * 16 + quad * 4) = pk;
        }
        // intra-wave LDS write->read: ordered via lgkmcnt (compiler-inserted)
#pragma unroll
        for (int ng = 0; ng < 2; ++ng) {
            // B-operand P: B[k=n][col=m], lane: col=l15, k = ng*32+quad*8+j
            bf16x8 pf = *(const bf16x8*)(pw + l15 * PSTR + ng * 32 + quad * 8);
            // A-operand V: A[r=i][k=n]
            bf16x8 v0 = *(const bf16x8*)(Vt + l15 * VSTR + ng * 32 + quad * 8);
            bf16x8 v1 = *(const bf16x8*)(Vt + (16 + l15) * VSTR + ng * 32 + quad * 8);
            acc0 = __builtin_amdgcn_mfma_f32_16x16x32_bf16(v0, pf, acc0, 0, 0, 0);
            acc1 = __builtin_amdgcn_mfma_f32_16x16x32_bf16(v1, pf, acc1, 0, 0, 0);
        }
    }

    // denominator: sum partial l over the 4 quads sharing column m
    lsum += __shfl_xor(lsum, 16, 64);
    lsum += __shfl_xor(lsum, 32, 64);
    const float inv = 1.f / lsum;

    const float* pb = points + (size_t)b * 256 * 4096;
    float* zb = z + (size_t)b * 256 * 4096;
#pragma unroll
    for (int half = 0; half < 2; ++half) {
        f32x4 a = half ? acc1 : acc0;
#pragma unroll
        for (int r = 0; r < 4; ++r) {
            int i = half * 16 + quad * 4 + r;             // C/D row mapping
            size_t off = (size_t)(i * 8 + g) * 4096 + m;  // channel shuffle
            zb[off] = a[r] * inv + pb[off];               // + identity
        }
    }
}

// ---------------------------------------------------------------------------
// Kernel 3: GroupNorm stats. 64 blocks = (b, gn_group); 8 ch x 4096 elements
// ---------------------------------------------------------------------------
__global__ __launch_bounds__(256) void gn_stats(const float* __restrict__ z,
                                                float* __restrict__ stats)
{
    const int blk = blockIdx.x;
    const int tid = threadIdx.x;
    const float4* p = (const float4*)(z + (size_t)blk * 32768);
    float s = 0.f, ss = 0.f;
    for (int k = tid; k < 8192; k += 256) {
        float4 v = p[k];
        s  += v.x + v.y + v.z + v.w;
        ss += v.x * v.x + v.y * v.y + v.z * v.z + v.w * v.w;
    }
#pragma unroll
    for (int off = 32; off > 0; off >>= 1) {
        s  += __shfl_down(s, off, 64);
        ss += __shfl_down(ss, off, 64);
    }
    __shared__ float red[8];
    const int w = tid >> 6;
    if ((tid & 63) == 0) { red[w * 2] = s; red[w * 2 + 1] = ss; }
    __syncthreads();
    if (tid == 0) {
        s  = red[0] + red[2] + red[4] + red[6];
        ss = red[1] + red[3] + red[5] + red[7];
        float mean = s * (1.f / 32768.f);
        float var  = ss * (1.f / 32768.f) - mean * mean;
        stats[blk * 2]     = mean;
        stats[blk * 2 + 1] = rsqrtf(var + 1e-5f);
    }
}

// ---------------------------------------------------------------------------
// Kernel 4: GroupNorm apply, in place on d_out.
// ---------------------------------------------------------------------------
__global__ __launch_bounds__(256) void gn_apply(float* __restrict__ z,
                                                const float* __restrict__ stats,
                                                const float* __restrict__ gw,
                                                const float* __restrict__ gb)
{
    const int idx = blockIdx.x * 256 + threadIdx.x;  // float4 index
    float4* p = (float4*)z;
    float4 v = p[idx];
    const int chg = idx >> 10;       // global channel b*256+ch
    const int blk = chg >> 3;        // stats slot = b*32 + ch/8
    const int ch  = chg & 255;
    const float mean = stats[blk * 2], rstd = stats[blk * 2 + 1];
    const float w  = gw[ch] * rstd;
    const float bb = gb[ch] - mean * w;
    v.x = v.x * w + bb; v.y = v.y * w + bb;
    v.z = v.z * w + bb; v.w = v.w * w + bb;
    p[idx] = v;
}

extern "C" void kernel_launch(void* const* d_in, const int* in_sizes, int n_in,
                              void* d_out, int out_size, void* d_ws, size_t ws_size,
                              hipStream_t stream)
{
    const float* points = (const float*)d_in[0];
    const float* conv_w = (const float*)d_in[1];
    const float* conv_b = (const float*)d_in[2];
    const float* gn_w   = (const float*)d_in[3];
    const float* gn_b   = (const float*)d_in[4];
    float* out = (float*)d_out;
    char* ws = (char*)d_ws;
    unsigned short* xqT = (unsigned short*)ws;                             // 4 MB
    unsigned short* xv  = (unsigned short*)(ws + (size_t)4 * 1024 * 1024); // 4 MB
    float* stats = (float*)(ws + (size_t)8 * 1024 * 1024);                 // 512 B

    conv_kernel<<<256, 256, 0, stream>>>(points, conv_w, conv_b, xqT, xv);
    attn_kernel<<<dim3(64, 16), 256, 0, stream>>>(xqT, xv, points, out);
    gn_stats<<<64, 256, 0, stream>>>(out, stats);
    gn_apply<<<2048, 256, 0, stream>>>(out, stats, gn_w, gn_b);
}

// Round 7
// 171.849 us; speedup vs baseline: 4.3328x; 1.1097x over previous
//
#include <hip/hip_runtime.h>

typedef __attribute__((ext_vector_type(8))) short bf16x8;
typedef __attribute__((ext_vector_type(4))) short bf16x4;
typedef __attribute__((ext_vector_type(4))) float f32x4;

#if __has_builtin(__builtin_amdgcn_exp2f)
#define EXP2(x) __builtin_amdgcn_exp2f(x)
#else
#define EXP2(x) exp2f(x)
#endif

__device__ __forceinline__ unsigned short f2bf(float f) {
    union { float f; unsigned int u; } v; v.f = f;
    unsigned int r = v.u + 0x7fffu + ((v.u >> 16) & 1u);
    return (unsigned short)(r >> 16);
}

__device__ __forceinline__ float asf(unsigned int u) {
    union { unsigned int u; float f; } v; v.u = u; return v.f;
}

// sqrt( (1/sqrt(32)) * log2(e) ) — baked into BOTH xqT operands so QK^T
// emerges pre-multiplied by scale*log2e: exp2(raw score) == softmax numerator.
#define QK_PRESCALE 0.50500983f

// ---------------------------------------------------------------------------
// Kernel 1: grouped 1x1 conv.  x[h][i][n] = sum_j W[g][i][j] p[h][j][n] + b
// Writes xqT [h][n][i] (bf16, i contiguous, PRE-SCALED)  -> QK MFMA operands
//        xv  [h][i][n] (bf16, n contiguous)              -> PV A-op (V=elu(x))
// ---------------------------------------------------------------------------
__global__ __launch_bounds__(256) void conv_kernel(
    const float* __restrict__ points, const float* __restrict__ conv_w,
    const float* __restrict__ conv_b,
    unsigned short* __restrict__ xqT, unsigned short* __restrict__ xv)
{
    __shared__ float w[1024];
    const int h  = blockIdx.x >> 4;   // 16 heads
    const int nc = blockIdx.x & 15;   // 16 n-chunks of 256
    const int g  = h & 7;
    const int tid = threadIdx.x;
    const float* wg = conv_w + g * 1024;
    for (int k = tid; k < 1024; k += 256) w[k] = wg[k];
    __syncthreads();
    const int n = nc * 256 + tid;
    const float* p = points + (size_t)h * 32 * 4096 + n;
    float pv[32];
#pragma unroll
    for (int j = 0; j < 32; ++j) pv[j] = p[(size_t)j * 4096];
    float out[32];
#pragma unroll
    for (int i = 0; i < 32; ++i) {
        float acc = conv_b[g * 32 + i];
#pragma unroll
        for (int j = 0; j < 32; ++j) acc += w[i * 32 + j] * pv[j];
        out[i] = acc;
    }
    unsigned short tq[32];
#pragma unroll
    for (int i = 0; i < 32; ++i) tq[i] = f2bf(out[i] * QK_PRESCALE);
    bf16x8* dst = (bf16x8*)(xqT + ((size_t)h * 4096 + n) * 32);
#pragma unroll
    for (int t = 0; t < 4; ++t) dst[t] = ((bf16x8*)tq)[t];
#pragma unroll
    for (int i = 0; i < 32; ++i) {
        float x = out[i];
        float e = x > 0.f ? x : (__expf(x) - 1.f);   // elu
        xv[((size_t)h * 32 + i) * 4096 + n] = f2bf(e);
    }
}

// ---------------------------------------------------------------------------
// Kernel 2: flash attention. R6 structure (measured 106.5us) with two
// incremental changes ONLY:
//   (a) 128-key staging chunks, grid UNCHANGED (1024 blocks): barrier pairs
//       per block 64 -> 32.  LDS 18.9 -> 27.5 KB (still >= 5 blocks/CU cap,
//       grid-limited at 4 -> occupancy unchanged).
//   (b) register prefetch: next chunk's K/V global loads issue right after
//       the staging barrier, overlapping compute; consumed at next staging.
// Compute loop / P-transpose / epilogue byte-identical to R6.
// ---------------------------------------------------------------------------
#define KSTR 40    // 32 + 8 pad shorts
#define VSTR 136   // 128 + 8 pad shorts
#define PSTR 72    // 64 + 8 pad shorts

__device__ __forceinline__ bf16x4 exp_pack(f32x4 sc, float& lsum) {
    union { float f; unsigned int u; } e0, e1, e2, e3;
    e0.f = EXP2(sc[0]); e1.f = EXP2(sc[1]); e2.f = EXP2(sc[2]); e3.f = EXP2(sc[3]);
    unsigned int t0 = e0.u & 0xffff0000u, t1 = e1.u & 0xffff0000u;
    unsigned int t2 = e2.u & 0xffff0000u, t3 = e3.u & 0xffff0000u;
    lsum += (asf(t0) + asf(t1)) + (asf(t2) + asf(t3));
    union { unsigned int d[2]; bf16x4 v; } pk;
    pk.d[0] = (t0 >> 16) | t1;
    pk.d[1] = (t2 >> 16) | t3;
    return pk.v;
}

__global__ __launch_bounds__(256) void attn_kernel(
    const unsigned short* __restrict__ xqT,
    const unsigned short* __restrict__ xv,
    const float* __restrict__ points,
    float* __restrict__ z)
{
    __shared__ unsigned short Kt[128 * KSTR];   // [n][i]   10240 B
    __shared__ unsigned short Vt[32 * VSTR];    // [i][n]    8704 B
    __shared__ unsigned short Pl[4][16 * PSTR]; // per-wave  9216 B

    const int h  = blockIdx.y;
    const int b = h >> 3, g = h & 7;
    const int tid = threadIdx.x;
    const int wv = tid >> 6, lane = tid & 63;
    const int quad = lane >> 4, l15 = lane & 15;

    const int m = blockIdx.x * 64 + wv * 16 + l15;   // this lane's query col

    const unsigned short* kbase = xqT + (size_t)h * 4096 * 32;
    const unsigned short* vbase = xv  + (size_t)h * 32 * 4096;

    // Q fragment (B-operand): col=l15, k=quad*8+j
    const bf16x8 qfrag = *(const bf16x8*)(kbase + (size_t)m * 32 + quad * 8);

    f32x4 acc0 = {0.f, 0.f, 0.f, 0.f};   // O rows i = 0..15
    f32x4 acc1 = {0.f, 0.f, 0.f, 0.f};   // O rows i = 16..31
    float lsum = 0.f;

    const int kr = tid >> 2, kc = (tid & 3) * 8;   // K staging: [n][i], 2 rows
    const int vi = tid >> 3, vn = (tid & 7) * 8;   // V staging: [i][n], 2 cols

    unsigned short* pw = &Pl[wv][0];

    // ---- register prefetch pointers (advance by 128 keys per iter) ----
    const unsigned short* kptrA = kbase + (size_t)kr * 32 + kc;
    const unsigned short* kptrB = kbase + (size_t)(64 + kr) * 32 + kc;
    const unsigned short* vptr  = vbase + (size_t)vi * 4096 + vn;
    bf16x8 ka = *(const bf16x8*)kptrA;
    bf16x8 kb = *(const bf16x8*)kptrB;
    bf16x8 va = *(const bf16x8*)vptr;
    bf16x8 vb = *(const bf16x8*)(vptr + 64);

    for (int n0 = 0; n0 < 4096; n0 += 128) {
        __syncthreads();   // previous compute done -> safe to overwrite tiles
        *(bf16x8*)(Kt + kr * KSTR + kc)        = ka;
        *(bf16x8*)(Kt + (kr + 64) * KSTR + kc) = kb;
        *(bf16x8*)(Vt + vi * VSTR + vn)        = va;
        *(bf16x8*)(Vt + vi * VSTR + vn + 64)   = vb;
        __syncthreads();   // tiles visible to all waves

        if (n0 + 128 < 4096) {   // prefetch next chunk; overlaps compute below
            kptrA += 128 * 32; kptrB += 128 * 32; vptr += 128;
            ka = *(const bf16x8*)kptrA;
            kb = *(const bf16x8*)kptrB;
            va = *(const bf16x8*)vptr;
            vb = *(const bf16x8*)(vptr + 64);
        }

#pragma unroll
        for (int sub = 0; sub < 2; ++sub) {
#pragma unroll
            for (int s = 0; s < 4; ++s) {
                // A-operand K^T: A[r=n][k=i], lane r=l15
                bf16x8 kf = *(const bf16x8*)(
                    Kt + (sub * 64 + s * 16 + l15) * KSTR + quad * 8);
                f32x4 sc = __builtin_amdgcn_mfma_f32_16x16x32_bf16(
                    kf, qfrag, (f32x4){0.f, 0.f, 0.f, 0.f}, 0, 0, 0);
                // C/D: col=m=l15, row n = quad*4 + r  (within 16-key step)
                bf16x4 pk = exp_pack(sc, lsum);
                *(bf16x4*)(pw + l15 * PSTR + s * 16 + quad * 4) = pk;
            }
            // intra-wave LDS write->read: ordered via lgkmcnt
#pragma unroll
            for (int ng = 0; ng < 2; ++ng) {
                // B-operand P: col=l15, k = ng*32+quad*8+j
                bf16x8 pf = *(const bf16x8*)(pw + l15 * PSTR + ng * 32 + quad * 8);
                const int col = sub * 64 + ng * 32 + quad * 8;
                // A-operand V: A[r=i][k=n]
                bf16x8 v0 = *(const bf16x8*)(Vt + l15 * VSTR + col);
                bf16x8 v1 = *(const bf16x8*)(Vt + (16 + l15) * VSTR + col);
                acc0 = __builtin_amdgcn_mfma_f32_16x16x32_bf16(v0, pf, acc0, 0, 0, 0);
                acc1 = __builtin_amdgcn_mfma_f32_16x16x32_bf16(v1, pf, acc1, 0, 0, 0);
            }
        }
    }

    // denominator: sum partial l over the 4 quads sharing column m
    lsum += __shfl_xor(lsum, 16, 64);
    lsum += __shfl_xor(lsum, 32, 64);
    const float inv = 1.f / lsum;

    const float* pb = points + (size_t)b * 256 * 4096;
    float* zb = z + (size_t)b * 256 * 4096;
#pragma unroll
    for (int half = 0; half < 2; ++half) {
        f32x4 a = half ? acc1 : acc0;
#pragma unroll
        for (int r = 0; r < 4; ++r) {
            int i = half * 16 + quad * 4 + r;             // C/D row mapping
            size_t off = (size_t)(i * 8 + g) * 4096 + m;  // channel shuffle
            zb[off] = a[r] * inv + pb[off];               // + identity
        }
    }
}

// ---------------------------------------------------------------------------
// Kernel 3: GroupNorm stats. 64 blocks = (b, gn_group); 8 ch x 4096 elements
// ---------------------------------------------------------------------------
__global__ __launch_bounds__(256) void gn_stats(const float* __restrict__ z,
                                                float* __restrict__ stats)
{
    const int blk = blockIdx.x;
    const int tid = threadIdx.x;
    const float4* p = (const float4*)(z + (size_t)blk * 32768);
    float s = 0.f, ss = 0.f;
    for (int k = tid; k < 8192; k += 256) {
        float4 v = p[k];
        s  += v.x + v.y + v.z + v.w;
        ss += v.x * v.x + v.y * v.y + v.z * v.z + v.w * v.w;
    }
#pragma unroll
    for (int off = 32; off > 0; off >>= 1) {
        s  += __shfl_down(s, off, 64);
        ss += __shfl_down(ss, off, 64);
    }
    __shared__ float red[8];
    const int w = tid >> 6;
    if ((tid & 63) == 0) { red[w * 2] = s; red[w * 2 + 1] = ss; }
    __syncthreads();
    if (tid == 0) {
        s  = red[0] + red[2] + red[4] + red[6];
        ss = red[1] + red[3] + red[5] + red[7];
        float mean = s * (1.f / 32768.f);
        float var  = ss * (1.f / 32768.f) - mean * mean;
        stats[blk * 2]     = mean;
        stats[blk * 2 + 1] = rsqrtf(var + 1e-5f);
    }
}

// ---------------------------------------------------------------------------
// Kernel 4: GroupNorm apply, in place on d_out.
// ---------------------------------------------------------------------------
__global__ __launch_bounds__(256) void gn_apply(float* __restrict__ z,
                                                const float* __restrict__ stats,
                                                const float* __restrict__ gw,
                                                const float* __restrict__ gb)
{
    const int idx = blockIdx.x * 256 + threadIdx.x;  // float4 index
    float4* p = (float4*)z;
    float4 v = p[idx];
    const int chg = idx >> 10;       // global channel b*256+ch
    const int blk = chg >> 3;        // stats slot = b*32 + ch/8
    const int ch  = chg & 255;
    const float mean = stats[blk * 2], rstd = stats[blk * 2 + 1];
    const float w  = gw[ch] * rstd;
    const float bb = gb[ch] - mean * w;
    v.x = v.x * w + bb; v.y = v.y * w + bb;
    v.z = v.z * w + bb; v.w = v.w * w + bb;
    p[idx] = v;
}

extern "C" void kernel_launch(void* const* d_in, const int* in_sizes, int n_in,
                              void* d_out, int out_size, void* d_ws, size_t ws_size,
                              hipStream_t stream)
{
    const float* points = (const float*)d_in[0];
    const float* conv_w = (const float*)d_in[1];
    const float* conv_b = (const float*)d_in[2];
    const float* gn_w   = (const float*)d_in[3];
    const float* gn_b   = (const float*)d_in[4];
    float* out = (float*)d_out;
    char* ws = (char*)d_ws;
    unsigned short* xqT = (unsigned short*)ws;                             // 4 MB
    unsigned short* xv  = (unsigned short*)(ws + (size_t)4 * 1024 * 1024); // 4 MB
    float* stats = (float*)(ws + (size_t)8 * 1024 * 1024);                 // 512 B

    conv_kernel<<<256, 256, 0, stream>>>(points, conv_w, conv_b, xqT, xv);
    attn_kernel<<<dim3(64, 16), 256, 0, stream>>>(xqT, xv, points, out);
    gn_stats<<<64, 256, 0, stream>>>(out, stats);
    gn_apply<<<2048, 256, 0, stream>>>(out, stats, gn_w, gn_b);
}

// Round 8
// 161.080 us; speedup vs baseline: 4.6225x; 1.0669x over previous
//
#include <hip/hip_runtime.h>

typedef __attribute__((ext_vector_type(8))) short bf16x8;
typedef __attribute__((ext_vector_type(4))) short bf16x4;
typedef __attribute__((ext_vector_type(4))) float f32x4;

#if __has_builtin(__builtin_amdgcn_exp2f)
#define EXP2(x) __builtin_amdgcn_exp2f(x)
#else
#define EXP2(x) exp2f(x)
#endif

__device__ __forceinline__ unsigned short f2bf(float f) {
    union { float f; unsigned int u; } v; v.f = f;
    unsigned int r = v.u + 0x7fffu + ((v.u >> 16) & 1u);
    return (unsigned short)(r >> 16);
}

__device__ __forceinline__ float asf(unsigned int u) {
    union { unsigned int u; float f; } v; v.u = u; return v.f;
}

// sqrt( (1/sqrt(32)) * log2(e) ) — baked into BOTH xqT operands so QK^T
// emerges pre-multiplied by scale*log2e: exp2(raw score) == softmax numerator.
#define QK_PRESCALE 0.50500983f

// ---------------------------------------------------------------------------
// Kernel 1: grouped 1x1 conv.  x[h][i][n] = sum_j W[g][i][j] p[h][j][n] + b
// Writes xqT [h][n][i] (bf16, i contiguous, PRE-SCALED)  -> QK MFMA operands
//        xv  [h][i][n] (bf16, n contiguous)              -> PV A-op (V=elu(x))
// ---------------------------------------------------------------------------
__global__ __launch_bounds__(256) void conv_kernel(
    const float* __restrict__ points, const float* __restrict__ conv_w,
    const float* __restrict__ conv_b,
    unsigned short* __restrict__ xqT, unsigned short* __restrict__ xv)
{
    __shared__ float w[1024];
    const int h  = blockIdx.x >> 4;   // 16 heads
    const int nc = blockIdx.x & 15;   // 16 n-chunks of 256
    const int g  = h & 7;
    const int tid = threadIdx.x;
    const float* wg = conv_w + g * 1024;
    for (int k = tid; k < 1024; k += 256) w[k] = wg[k];
    __syncthreads();
    const int n = nc * 256 + tid;
    const float* p = points + (size_t)h * 32 * 4096 + n;
    float pv[32];
#pragma unroll
    for (int j = 0; j < 32; ++j) pv[j] = p[(size_t)j * 4096];
    float out[32];
#pragma unroll
    for (int i = 0; i < 32; ++i) {
        float acc = conv_b[g * 32 + i];
        const float4* w4 = (const float4*)(w + i * 32);   // ds_read_b128
#pragma unroll
        for (int j4 = 0; j4 < 8; ++j4) {
            float4 ww = w4[j4];
            acc += ww.x * pv[j4 * 4]     + ww.y * pv[j4 * 4 + 1]
                 + ww.z * pv[j4 * 4 + 2] + ww.w * pv[j4 * 4 + 3];
        }
        out[i] = acc;
    }
    unsigned short tq[32];
#pragma unroll
    for (int i = 0; i < 32; ++i) tq[i] = f2bf(out[i] * QK_PRESCALE);
    bf16x8* dst = (bf16x8*)(xqT + ((size_t)h * 4096 + n) * 32);
#pragma unroll
    for (int t = 0; t < 4; ++t) dst[t] = ((bf16x8*)tq)[t];
#pragma unroll
    for (int i = 0; i < 32; ++i) {
        float x = out[i];
        float e = x > 0.f ? x : (__expf(x) - 1.f);   // elu
        xv[((size_t)h * 32 + i) * 4096 + n] = f2bf(e);
    }
}

// ---------------------------------------------------------------------------
// Kernel 2: flash attention. R7 structure FROZEN (measured 88.6us): 1024
// blocks, 128-key staging chunks, register prefetch across the barrier,
// per-wave P LDS round-trip. Only change: exp_pack uses v_cvt_pk_bf16_f32
// (RNE, 1 inst per 2 scores) when available; denominator sums raw exp
// values (RNE is unbiased -> no systematic softmax bias).
// ---------------------------------------------------------------------------
#define KSTR 40    // 32 + 8 pad shorts
#define VSTR 136   // 128 + 8 pad shorts
#define PSTR 72    // 64 + 8 pad shorts

#if __has_builtin(__builtin_amdgcn_cvt_pk_bf16_f32)
typedef __attribute__((ext_vector_type(2))) __bf16 bf16x2v;
__device__ __forceinline__ bf16x4 exp_pack(f32x4 sc, float& lsum) {
    float e0 = EXP2(sc[0]), e1 = EXP2(sc[1]);
    float e2 = EXP2(sc[2]), e3 = EXP2(sc[3]);
    lsum += (e0 + e1) + (e2 + e3);
    union { bf16x2v v[2]; bf16x4 s; } u;
    u.v[0] = __builtin_amdgcn_cvt_pk_bf16_f32(e0, e1);  // lo=e0, hi=e1
    u.v[1] = __builtin_amdgcn_cvt_pk_bf16_f32(e2, e3);
    return u.s;
}
#else
__device__ __forceinline__ bf16x4 exp_pack(f32x4 sc, float& lsum) {
    union { float f; unsigned int u; } e0, e1, e2, e3;
    e0.f = EXP2(sc[0]); e1.f = EXP2(sc[1]); e2.f = EXP2(sc[2]); e3.f = EXP2(sc[3]);
    unsigned int t0 = e0.u & 0xffff0000u, t1 = e1.u & 0xffff0000u;
    unsigned int t2 = e2.u & 0xffff0000u, t3 = e3.u & 0xffff0000u;
    lsum += (asf(t0) + asf(t1)) + (asf(t2) + asf(t3));
    union { unsigned int d[2]; bf16x4 v; } pk;
    pk.d[0] = (t0 >> 16) | t1;
    pk.d[1] = (t2 >> 16) | t3;
    return pk.v;
}
#endif

__global__ __launch_bounds__(256) void attn_kernel(
    const unsigned short* __restrict__ xqT,
    const unsigned short* __restrict__ xv,
    const float* __restrict__ points,
    float* __restrict__ z)
{
    __shared__ unsigned short Kt[128 * KSTR];   // [n][i]   10240 B
    __shared__ unsigned short Vt[32 * VSTR];    // [i][n]    8704 B
    __shared__ unsigned short Pl[4][16 * PSTR]; // per-wave  9216 B

    const int h  = blockIdx.y;
    const int b = h >> 3, g = h & 7;
    const int tid = threadIdx.x;
    const int wv = tid >> 6, lane = tid & 63;
    const int quad = lane >> 4, l15 = lane & 15;

    const int m = blockIdx.x * 64 + wv * 16 + l15;   // this lane's query col

    const unsigned short* kbase = xqT + (size_t)h * 4096 * 32;
    const unsigned short* vbase = xv  + (size_t)h * 32 * 4096;

    // Q fragment (B-operand): col=l15, k=quad*8+j
    const bf16x8 qfrag = *(const bf16x8*)(kbase + (size_t)m * 32 + quad * 8);

    f32x4 acc0 = {0.f, 0.f, 0.f, 0.f};   // O rows i = 0..15
    f32x4 acc1 = {0.f, 0.f, 0.f, 0.f};   // O rows i = 16..31
    float lsum = 0.f;

    const int kr = tid >> 2, kc = (tid & 3) * 8;   // K staging: [n][i], 2 rows
    const int vi = tid >> 3, vn = (tid & 7) * 8;   // V staging: [i][n], 2 cols

    unsigned short* pw = &Pl[wv][0];

    // ---- register prefetch pointers (advance by 128 keys per iter) ----
    const unsigned short* kptrA = kbase + (size_t)kr * 32 + kc;
    const unsigned short* kptrB = kbase + (size_t)(64 + kr) * 32 + kc;
    const unsigned short* vptr  = vbase + (size_t)vi * 4096 + vn;
    bf16x8 ka = *(const bf16x8*)kptrA;
    bf16x8 kb = *(const bf16x8*)kptrB;
    bf16x8 va = *(const bf16x8*)vptr;
    bf16x8 vb = *(const bf16x8*)(vptr + 64);

    for (int n0 = 0; n0 < 4096; n0 += 128) {
        __syncthreads();   // previous compute done -> safe to overwrite tiles
        *(bf16x8*)(Kt + kr * KSTR + kc)        = ka;
        *(bf16x8*)(Kt + (kr + 64) * KSTR + kc) = kb;
        *(bf16x8*)(Vt + vi * VSTR + vn)        = va;
        *(bf16x8*)(Vt + vi * VSTR + vn + 64)   = vb;
        __syncthreads();   // tiles visible to all waves

        if (n0 + 128 < 4096) {   // prefetch next chunk; overlaps compute below
            kptrA += 128 * 32; kptrB += 128 * 32; vptr += 128;
            ka = *(const bf16x8*)kptrA;
            kb = *(const bf16x8*)kptrB;
            va = *(const bf16x8*)vptr;
            vb = *(const bf16x8*)(vptr + 64);
        }

#pragma unroll
        for (int sub = 0; sub < 2; ++sub) {
#pragma unroll
            for (int s = 0; s < 4; ++s) {
                // A-operand K^T: A[r=n][k=i], lane r=l15
                bf16x8 kf = *(const bf16x8*)(
                    Kt + (sub * 64 + s * 16 + l15) * KSTR + quad * 8);
                f32x4 sc = __builtin_amdgcn_mfma_f32_16x16x32_bf16(
                    kf, qfrag, (f32x4){0.f, 0.f, 0.f, 0.f}, 0, 0, 0);
                // C/D: col=m=l15, row n = quad*4 + r  (within 16-key step)
                bf16x4 pk = exp_pack(sc, lsum);
                *(bf16x4*)(pw + l15 * PSTR + s * 16 + quad * 4) = pk;
            }
            // intra-wave LDS write->read: ordered via lgkmcnt
#pragma unroll
            for (int ng = 0; ng < 2; ++ng) {
                // B-operand P: col=l15, k = ng*32+quad*8+j
                bf16x8 pf = *(const bf16x8*)(pw + l15 * PSTR + ng * 32 + quad * 8);
                const int col = sub * 64 + ng * 32 + quad * 8;
                // A-operand V: A[r=i][k=n]
                bf16x8 v0 = *(const bf16x8*)(Vt + l15 * VSTR + col);
                bf16x8 v1 = *(const bf16x8*)(Vt + (16 + l15) * VSTR + col);
                acc0 = __builtin_amdgcn_mfma_f32_16x16x32_bf16(v0, pf, acc0, 0, 0, 0);
                acc1 = __builtin_amdgcn_mfma_f32_16x16x32_bf16(v1, pf, acc1, 0, 0, 0);
            }
        }
    }

    // denominator: sum partial l over the 4 quads sharing column m
    lsum += __shfl_xor(lsum, 16, 64);
    lsum += __shfl_xor(lsum, 32, 64);
    const float inv = 1.f / lsum;

    const float* pb = points + (size_t)b * 256 * 4096;
    float* zb = z + (size_t)b * 256 * 4096;
#pragma unroll
    for (int half = 0; half < 2; ++half) {
        f32x4 a = half ? acc1 : acc0;
#pragma unroll
        for (int r = 0; r < 4; ++r) {
            int i = half * 16 + quad * 4 + r;             // C/D row mapping
            size_t off = (size_t)(i * 8 + g) * 4096 + m;  // channel shuffle
            zb[off] = a[r] * inv + pb[off];               // + identity
        }
    }
}

// ---------------------------------------------------------------------------
// Kernel 3: GroupNorm partial stats. 256 blocks = 4 per (b, gn_group),
// DISTINCT output slots (no atomics). Each block: 8192 floats (32 KB).
// ---------------------------------------------------------------------------
__global__ __launch_bounds__(256) void gn_stats(const float* __restrict__ z,
                                                float* __restrict__ pstats)
{
    const int blk = blockIdx.x;              // group*4 + quarter
    const int tid = threadIdx.x;
    const float4* p = (const float4*)(z + (size_t)blk * 8192);
    float s = 0.f, ss = 0.f;
    for (int k = tid; k < 2048; k += 256) {
        float4 v = p[k];
        s  += v.x + v.y + v.z + v.w;
        ss += v.x * v.x + v.y * v.y + v.z * v.z + v.w * v.w;
    }
#pragma unroll
    for (int off = 32; off > 0; off >>= 1) {
        s  += __shfl_down(s, off, 64);
        ss += __shfl_down(ss, off, 64);
    }
    __shared__ float red[8];
    const int w = tid >> 6;
    if ((tid & 63) == 0) { red[w * 2] = s; red[w * 2 + 1] = ss; }
    __syncthreads();
    if (tid == 0) {
        s  = red[0] + red[2] + red[4] + red[6];
        ss = red[1] + red[3] + red[5] + red[7];
        pstats[blk * 2]     = s;
        pstats[blk * 2 + 1] = ss;
    }
}

// ---------------------------------------------------------------------------
// Kernel 4: GroupNorm apply, in place on d_out; combines 4 partial sums.
// ---------------------------------------------------------------------------
__global__ __launch_bounds__(256) void gn_apply(float* __restrict__ z,
                                                const float* __restrict__ pstats,
                                                const float* __restrict__ gw,
                                                const float* __restrict__ gb)
{
    const int idx = blockIdx.x * 256 + threadIdx.x;  // float4 index
    float4* p = (float4*)z;
    float4 v = p[idx];
    const int chg = idx >> 10;       // global channel b*256+ch
    const int grp = chg >> 3;        // group slot = b*32 + ch/8
    const int ch  = chg & 255;
    const float4 s4  = *(const float4*)(pstats + grp * 8);      // s0,ss0,s1,ss1
    const float4 s4b = *(const float4*)(pstats + grp * 8 + 4);  // s2,ss2,s3,ss3
    const float s  = s4.x + s4.z + s4b.x + s4b.z;
    const float ss = s4.y + s4.w + s4b.y + s4b.w;
    const float mean = s * (1.f / 32768.f);
    const float var  = ss * (1.f / 32768.f) - mean * mean;
    const float rstd = rsqrtf(var + 1e-5f);
    const float w  = gw[ch] * rstd;
    const float bb = gb[ch] - mean * w;
    v.x = v.x * w + bb; v.y = v.y * w + bb;
    v.z = v.z * w + bb; v.w = v.w * w + bb;
    p[idx] = v;
}

extern "C" void kernel_launch(void* const* d_in, const int* in_sizes, int n_in,
                              void* d_out, int out_size, void* d_ws, size_t ws_size,
                              hipStream_t stream)
{
    const float* points = (const float*)d_in[0];
    const float* conv_w = (const float*)d_in[1];
    const float* conv_b = (const float*)d_in[2];
    const float* gn_w   = (const float*)d_in[3];
    const float* gn_b   = (const float*)d_in[4];
    float* out = (float*)d_out;
    char* ws = (char*)d_ws;
    unsigned short* xqT = (unsigned short*)ws;                             // 4 MB
    unsigned short* xv  = (unsigned short*)(ws + (size_t)4 * 1024 * 1024); // 4 MB
    float* pstats = (float*)(ws + (size_t)8 * 1024 * 1024);                // 2 KB

    conv_kernel<<<256, 256, 0, stream>>>(points, conv_w, conv_b, xqT, xv);
    attn_kernel<<<dim3(64, 16), 256, 0, stream>>>(xqT, xv, points, out);
    gn_stats<<<256, 256, 0, stream>>>(out, pstats);
    gn_apply<<<2048, 256, 0, stream>>>(out, pstats, gn_w, gn_b);
}

// Round 9
// 152.876 us; speedup vs baseline: 4.8705x; 1.0537x over previous
//
#include <hip/hip_runtime.h>

typedef __attribute__((ext_vector_type(8))) short bf16x8;
typedef __attribute__((ext_vector_type(4))) short bf16x4;
typedef __attribute__((ext_vector_type(4))) float f32x4;

#if __has_builtin(__builtin_amdgcn_exp2f)
#define EXP2(x) __builtin_amdgcn_exp2f(x)
#else
#define EXP2(x) exp2f(x)
#endif

__device__ __forceinline__ unsigned short f2bf(float f) {
    union { float f; unsigned int u; } v; v.f = f;
    unsigned int r = v.u + 0x7fffu + ((v.u >> 16) & 1u);
    return (unsigned short)(r >> 16);
}

__device__ __forceinline__ float asf(unsigned int u) {
    union { unsigned int u; float f; } v; v.u = u; return v.f;
}

// sqrt( (1/sqrt(32)) * log2(e) ) — baked into BOTH xqT operands so QK^T
// emerges pre-multiplied by scale*log2e: exp2(raw score) == softmax numerator.
#define QK_PRESCALE 0.50500983f

// ---------------------------------------------------------------------------
// Kernel 1: grouped 1x1 conv, 1024 blocks (was 256 -> 1 block/CU).
// block = 64 n-positions x 4 i-groups (one wave per i-group of 8 channels).
// Writes xqT [h][n][i] (bf16, i contiguous, PRE-SCALED)  -> QK MFMA operands
//        xv  [h][i][n] (bf16, n contiguous)              -> PV A-op (V=elu(x))
// ---------------------------------------------------------------------------
__global__ __launch_bounds__(256) void conv_kernel(
    const float* __restrict__ points, const float* __restrict__ conv_w,
    const float* __restrict__ conv_b,
    unsigned short* __restrict__ xqT, unsigned short* __restrict__ xv)
{
    __shared__ float w[1024];
    const int h  = blockIdx.x >> 6;   // 16 heads
    const int nc = blockIdx.x & 63;   // 64 n-chunks of 64
    const int g  = h & 7;
    const int tid = threadIdx.x;
    const float* wg = conv_w + g * 1024;
    for (int k = tid; k < 1024; k += 256) w[k] = wg[k];
    __syncthreads();
    const int n  = nc * 64 + (tid & 63);
    const int ig = tid >> 6;          // wave id -> channels [ig*8, ig*8+8)
    const float* p = points + (size_t)h * 32 * 4096 + n;
    float pv[32];
#pragma unroll
    for (int j = 0; j < 32; ++j) pv[j] = p[(size_t)j * 4096];
    float out[8];
#pragma unroll
    for (int ii = 0; ii < 8; ++ii) {
        const int i = ig * 8 + ii;
        float acc = conv_b[g * 32 + i];
        const float4* w4 = (const float4*)(w + i * 32);   // ds_read_b128
#pragma unroll
        for (int j4 = 0; j4 < 8; ++j4) {
            float4 ww = w4[j4];
            acc += ww.x * pv[j4 * 4]     + ww.y * pv[j4 * 4 + 1]
                 + ww.z * pv[j4 * 4 + 2] + ww.w * pv[j4 * 4 + 3];
        }
        out[ii] = acc;
    }
    unsigned short tq[8];
#pragma unroll
    for (int ii = 0; ii < 8; ++ii) tq[ii] = f2bf(out[ii] * QK_PRESCALE);
    *(bf16x8*)(xqT + ((size_t)h * 4096 + n) * 32 + ig * 8) = *(bf16x8*)tq;
#pragma unroll
    for (int ii = 0; ii < 8; ++ii) {
        float x = out[ii];
        float e = x > 0.f ? x : (__expf(x) - 1.f);   // elu
        xv[((size_t)h * 32 + ig * 8 + ii) * 4096 + n] = f2bf(e);
    }
}

// ---------------------------------------------------------------------------
// Kernel 2: flash attention. R7/R8 skeleton (1024 blocks, 128-key chunks,
// prefetch across the barrier) with the LDS diet:
//   K fragments now load DIRECT global -> registers, double-buffered with a
//   one-chunk prefetch distance (the wave's 8 fragment loads are a perfect
//   permutation of one aligned 1KB block -> single coalesced dwordx4 each;
//   4 waves/block re-hit L1). Removes 2 w128 + 8 r128 LDS instrs per
//   wave-chunk (~36% of the LDS-pipe demand that R8 analysis showed was
//   ~82% busy — the real bottleneck). V + P stay in LDS.
// __launch_bounds__(256,4) pins VGPR <= 128 so 4 blocks/CU survives.
// ---------------------------------------------------------------------------
#define VSTR 136   // 128 + 8 pad shorts
#define PSTR 72    // 64 + 8 pad shorts

#if __has_builtin(__builtin_amdgcn_cvt_pk_bf16_f32)
typedef __attribute__((ext_vector_type(2))) __bf16 bf16x2v;
__device__ __forceinline__ bf16x4 exp_pack(f32x4 sc, float& lsum) {
    float e0 = EXP2(sc[0]), e1 = EXP2(sc[1]);
    float e2 = EXP2(sc[2]), e3 = EXP2(sc[3]);
    lsum += (e0 + e1) + (e2 + e3);
    union { bf16x2v v[2]; bf16x4 s; } u;
    u.v[0] = __builtin_amdgcn_cvt_pk_bf16_f32(e0, e1);
    u.v[1] = __builtin_amdgcn_cvt_pk_bf16_f32(e2, e3);
    return u.s;
}
#else
__device__ __forceinline__ bf16x4 exp_pack(f32x4 sc, float& lsum) {
    union { float f; unsigned int u; } e0, e1, e2, e3;
    e0.f = EXP2(sc[0]); e1.f = EXP2(sc[1]); e2.f = EXP2(sc[2]); e3.f = EXP2(sc[3]);
    unsigned int t0 = e0.u & 0xffff0000u, t1 = e1.u & 0xffff0000u;
    unsigned int t2 = e2.u & 0xffff0000u, t3 = e3.u & 0xffff0000u;
    lsum += (asf(t0) + asf(t1)) + (asf(t2) + asf(t3));
    union { unsigned int d[2]; bf16x4 v; } pk;
    pk.d[0] = (t0 >> 16) | t1;
    pk.d[1] = (t2 >> 16) | t3;
    return pk.v;
}
#endif

// One 128-key chunk: stage V, prefetch next V (regs) + next K frags (KP),
// compute 8 x 16-key steps from current K frags (KU). pf wraps to 0 on the
// last chunk (harmless valid-memory prefetch, no branch).
#define CHUNK(C0, KU, KP)                                                      \
    {                                                                          \
        __syncthreads();                                                       \
        *(bf16x8*)(Vt + vi * VSTR + vn)      = va;                             \
        *(bf16x8*)(Vt + vi * VSTR + vn + 64) = vb;                             \
        __syncthreads();                                                       \
        const int pfb = ((C0) + 128) & 4095;                                   \
        va = *(const bf16x8*)(vbase + (size_t)vi * 4096 + pfb + vn);           \
        vb = *(const bf16x8*)(vbase + (size_t)vi * 4096 + pfb + vn + 64);      \
        _Pragma("unroll")                                                      \
        for (int s8 = 0; s8 < 8; ++s8)                                         \
            KP[s8] = *(const bf16x8*)(kfp + (size_t)(pfb + s8 * 16) * 32);     \
        _Pragma("unroll")                                                      \
        for (int sub = 0; sub < 2; ++sub) {                                    \
            _Pragma("unroll")                                                  \
            for (int s = 0; s < 4; ++s) {                                      \
                f32x4 sc = __builtin_amdgcn_mfma_f32_16x16x32_bf16(            \
                    KU[sub * 4 + s], qfrag, (f32x4){0.f, 0.f, 0.f, 0.f},       \
                    0, 0, 0);                                                  \
                bf16x4 pk = exp_pack(sc, lsum);                                \
                *(bf16x4*)(pw + l15 * PSTR + s * 16 + quad * 4) = pk;          \
            }                                                                  \
            _Pragma("unroll")                                                  \
            for (int ng = 0; ng < 2; ++ng) {                                   \
                bf16x8 pfrag = *(const bf16x8*)(pw + l15 * PSTR + ng * 32 +    \
                                                quad * 8);                     \
                const int col = sub * 64 + ng * 32 + quad * 8;                 \
                bf16x8 v0 = *(const bf16x8*)(Vt + l15 * VSTR + col);           \
                bf16x8 v1 = *(const bf16x8*)(Vt + (16 + l15) * VSTR + col);    \
                acc0 = __builtin_amdgcn_mfma_f32_16x16x32_bf16(v0, pfrag,      \
                                                               acc0, 0, 0, 0); \
                acc1 = __builtin_amdgcn_mfma_f32_16x16x32_bf16(v1, pfrag,      \
                                                               acc1, 0, 0, 0); \
            }                                                                  \
        }                                                                      \
    }

__global__ __launch_bounds__(256, 4) void attn_kernel(
    const unsigned short* __restrict__ xqT,
    const unsigned short* __restrict__ xv,
    const float* __restrict__ points,
    float* __restrict__ z)
{
    __shared__ unsigned short Vt[32 * VSTR];    // [i][n]    8704 B
    __shared__ unsigned short Pl[4][16 * PSTR]; // per-wave  9216 B

    const int h  = blockIdx.y;
    const int b = h >> 3, g = h & 7;
    const int tid = threadIdx.x;
    const int wv = tid >> 6, lane = tid & 63;
    const int quad = lane >> 4, l15 = lane & 15;

    const int m = blockIdx.x * 64 + wv * 16 + l15;   // this lane's query col

    const unsigned short* kbase = xqT + (size_t)h * 4096 * 32;
    const unsigned short* vbase = xv  + (size_t)h * 32 * 4096;

    // Q fragment (B-operand): col=l15, k=quad*8+j
    const bf16x8 qfrag = *(const bf16x8*)(kbase + (size_t)m * 32 + quad * 8);

    f32x4 acc0 = {0.f, 0.f, 0.f, 0.f};   // O rows i = 0..15
    f32x4 acc1 = {0.f, 0.f, 0.f, 0.f};   // O rows i = 16..31
    float lsum = 0.f;

    const int vi = tid >> 3, vn = (tid & 7) * 8;   // V staging: [i][n], 2 cols
    unsigned short* pw = &Pl[wv][0];

    // per-lane K-fragment base: row l15, cols quad*8..+8 (A-operand K^T).
    // For key block n: frag = kfp + n*32.  Wave's 8 frags of a chunk are a
    // permutation of one aligned 1KB block -> fully coalesced dwordx4 loads.
    const unsigned short* kfp = kbase + (size_t)l15 * 32 + quad * 8;

    // V staging prefetch regs (chunk 0)
    const unsigned short* vptr = vbase + (size_t)vi * 4096 + vn;
    bf16x8 va = *(const bf16x8*)vptr;
    bf16x8 vb = *(const bf16x8*)(vptr + 64);

    // K fragment double buffer (chunk 0 into kA)
    bf16x8 kA[8], kB[8];
#pragma unroll
    for (int s8 = 0; s8 < 8; ++s8)
        kA[s8] = *(const bf16x8*)(kfp + (size_t)(s8 * 16) * 32);

    for (int n0 = 0; n0 < 4096; n0 += 256) {
        CHUNK(n0,       kA, kB);
        CHUNK(n0 + 128, kB, kA);
    }

    // denominator: sum partial l over the 4 quads sharing column m
    lsum += __shfl_xor(lsum, 16, 64);
    lsum += __shfl_xor(lsum, 32, 64);
    const float inv = 1.f / lsum;

    const float* pb = points + (size_t)b * 256 * 4096;
    float* zb = z + (size_t)b * 256 * 4096;
#pragma unroll
    for (int half = 0; half < 2; ++half) {
        f32x4 a = half ? acc1 : acc0;
#pragma unroll
        for (int r = 0; r < 4; ++r) {
            int i = half * 16 + quad * 4 + r;             // C/D row mapping
            size_t off = (size_t)(i * 8 + g) * 4096 + m;  // channel shuffle
            zb[off] = a[r] * inv + pb[off];               // + identity
        }
    }
}

// ---------------------------------------------------------------------------
// Kernel 3: GroupNorm partial stats. 256 blocks = 4 per (b, gn_group),
// DISTINCT output slots (no atomics). Each block: 8192 floats (32 KB).
// ---------------------------------------------------------------------------
__global__ __launch_bounds__(256) void gn_stats(const float* __restrict__ z,
                                                float* __restrict__ pstats)
{
    const int blk = blockIdx.x;              // group*4 + quarter
    const int tid = threadIdx.x;
    const float4* p = (const float4*)(z + (size_t)blk * 8192);
    float s = 0.f, ss = 0.f;
    for (int k = tid; k < 2048; k += 256) {
        float4 v = p[k];
        s  += v.x + v.y + v.z + v.w;
        ss += v.x * v.x + v.y * v.y + v.z * v.z + v.w * v.w;
    }
#pragma unroll
    for (int off = 32; off > 0; off >>= 1) {
        s  += __shfl_down(s, off, 64);
        ss += __shfl_down(ss, off, 64);
    }
    __shared__ float red[8];
    const int w = tid >> 6;
    if ((tid & 63) == 0) { red[w * 2] = s; red[w * 2 + 1] = ss; }
    __syncthreads();
    if (tid == 0) {
        s  = red[0] + red[2] + red[4] + red[6];
        ss = red[1] + red[3] + red[5] + red[7];
        pstats[blk * 2]     = s;
        pstats[blk * 2 + 1] = ss;
    }
}

// ---------------------------------------------------------------------------
// Kernel 4: GroupNorm apply, in place on d_out; combines 4 partial sums.
// ---------------------------------------------------------------------------
__global__ __launch_bounds__(256) void gn_apply(float* __restrict__ z,
                                                const float* __restrict__ pstats,
                                                const float* __restrict__ gw,
                                                const float* __restrict__ gb)
{
    const int idx = blockIdx.x * 256 + threadIdx.x;  // float4 index
    float4* p = (float4*)z;
    float4 v = p[idx];
    const int chg = idx >> 10;       // global channel b*256+ch
    const int grp = chg >> 3;        // group slot = b*32 + ch/8
    const int ch  = chg & 255;
    const float4 s4  = *(const float4*)(pstats + grp * 8);      // s0,ss0,s1,ss1
    const float4 s4b = *(const float4*)(pstats + grp * 8 + 4);  // s2,ss2,s3,ss3
    const float s  = s4.x + s4.z + s4b.x + s4b.z;
    const float ss = s4.y + s4.w + s4b.y + s4b.w;
    const float mean = s * (1.f / 32768.f);
    const float var  = ss * (1.f / 32768.f) - mean * mean;
    const float rstd = rsqrtf(var + 1e-5f);
    const float w  = gw[ch] * rstd;
    const float bb = gb[ch] - mean * w;
    v.x = v.x * w + bb; v.y = v.y * w + bb;
    v.z = v.z * w + bb; v.w = v.w * w + bb;
    p[idx] = v;
}

extern "C" void kernel_launch(void* const* d_in, const int* in_sizes, int n_in,
                              void* d_out, int out_size, void* d_ws, size_t ws_size,
                              hipStream_t stream)
{
    const float* points = (const float*)d_in[0];
    const float* conv_w = (const float*)d_in[1];
    const float* conv_b = (const float*)d_in[2];
    const float* gn_w   = (const float*)d_in[3];
    const float* gn_b   = (const float*)d_in[4];
    float* out = (float*)d_out;
    char* ws = (char*)d_ws;
    unsigned short* xqT = (unsigned short*)ws;                             // 4 MB
    unsigned short* xv  = (unsigned short*)(ws + (size_t)4 * 1024 * 1024); // 4 MB
    float* pstats = (float*)(ws + (size_t)8 * 1024 * 1024);                // 2 KB

    conv_kernel<<<1024, 256, 0, stream>>>(points, conv_w, conv_b, xqT, xv);
    attn_kernel<<<dim3(64, 16), 256, 0, stream>>>(xqT, xv, points, out);
    gn_stats<<<256, 256, 0, stream>>>(out, pstats);
    gn_apply<<<2048, 256, 0, stream>>>(out, pstats, gn_w, gn_b);
}